// Round 6
// baseline (527.650 us; speedup 1.0000x reference)
//
#include <hip/hip_runtime.h>
#include <hip/hip_bf16.h>

typedef __hip_bfloat16 bf16;
typedef unsigned short ushort_t;
typedef unsigned int uint32;

typedef short short4_t __attribute__((ext_vector_type(4)));
typedef short short8_t __attribute__((ext_vector_type(8)));
typedef float float4_t __attribute__((ext_vector_type(4)));

union FragU { short4_t h[2]; short8_t v; };
union Frag16 { short8_t v; short s[8]; uint4 u; };

#define BIG 100000.0f

// ---------------------------------------------------------------------------
// weights [64co][64ci][3][3] f32  ->  [9tap][64co][64ci] bf16 bits
// ---------------------------------------------------------------------------
__global__ __launch_bounds__(256) void wtrans(const float* __restrict__ w,
                                              ushort_t* __restrict__ dst)
{
    int idx = blockIdx.x * 256 + threadIdx.x;  // 36864 total
    if (idx < 36864) {
        int ci = idx & 63, co = (idx >> 6) & 63, t = idx >> 12;
        bf16 h = (bf16)w[(co * 64 + ci) * 9 + t];
        dst[idx] = *(ushort_t*)&h;
    }
}

// ---------------------------------------------------------------------------
// NCHW f32 -> NHWC bf16 (C=64).  Block: one row-y, 64 x.  LDS transpose.
// ---------------------------------------------------------------------------
__global__ __launch_bounds__(256) void nchw_to_nhwc(
    const float* __restrict__ in,   // [B][64][H][W]
    ushort_t* __restrict__ out,     // [B][H][W][64]
    int H, int W)
{
    __shared__ ushort_t s[64 * 66];
    const int b = blockIdx.z, y = blockIdx.y, x0 = blockIdx.x * 64;
    const int tid = threadIdx.x;
    const long ibase = (long)b * 64 * H * W + (long)y * W + x0;
    {
        const int x = tid & 63, dc = tid >> 6;
        for (int c = dc; c < 64; c += 4) {
            bf16 h = (bf16)in[ibase + (long)c * H * W + x];
            s[c * 66 + x] = *(ushort_t*)&h;
        }
    }
    __syncthreads();
    {
        const int c = tid & 63, dx = tid >> 6;
        const long obase = ((long)b * H * W + (long)y * W + x0) * 64;
        for (int x = dx; x < 64; x += 4)
            out[obase + (long)x * 64 + c] = s[c * 66 + x];
    }
}

// ---------------------------------------------------------------------------
// conv 3x3 SAME, 64->64 + bias + relu, NHWC bf16, MFMA 16x16x32.
// ---------------------------------------------------------------------------
__global__ __launch_bounds__(256) void conv3x3_mfma(
    const ushort_t* __restrict__ in,   // [B][H][W][64] bf16
    ushort_t* __restrict__ out,        // [B][H][W][64] bf16
    const ushort_t* __restrict__ wt,   // [9][64][64] bf16
    const float* __restrict__ bias,    // [64] f32
    int H, int W)
{
    __shared__ ushort_t s_in[324 * 36];     // 23,328 B
    __shared__ ushort_t s_w[9 * 64 * 36];   // 41,472 B  (total 64,800 <= 64K)

    const int b = blockIdx.z;
    const int x0 = blockIdx.x * 16, y0 = blockIdx.y * 16;
    const int tid = threadIdx.x;
    const int lane = tid & 63, wv = tid >> 6;
    const int n = lane & 15, q = lane >> 4;   // n: M or N index, q: k-quad

    const long img = (long)b * H * W;

    float4_t acc[4][4];
#pragma unroll
    for (int mb = 0; mb < 4; ++mb)
#pragma unroll
        for (int j = 0; j < 4; ++j) acc[mb][j] = (float4_t){0.f, 0.f, 0.f, 0.f};

    for (int half = 0; half < 2; ++half) {
        __syncthreads();
        // ---- stage input patch: 324 px x 32 ci = 324*4 = 1296 chunks of 8
        for (int idx = tid; idx < 1296; idx += 256) {
            const int p = idx >> 2, c = idx & 3;
            const int py = p / 18, px = p - py * 18;
            const int gy = y0 - 1 + py, gx = x0 - 1 + px;
            uint4 d = {0u, 0u, 0u, 0u};
            if (gy >= 0 && gy < H && gx >= 0 && gx < W)
                d = *(const uint4*)(in + ((img + (long)gy * W + gx) << 6) + half * 32 + c * 8);
            ushort_t* dp = &s_in[p * 36 + c * 8];
            *(uint2*)dp       = make_uint2(d.x, d.y);
            *(uint2*)(dp + 4) = make_uint2(d.z, d.w);
        }
        // ---- stage weights: 9*64 = 576 rows x 32 ci = 2304 chunks
        for (int idx = tid; idx < 2304; idx += 256) {
            const int wc = idx >> 2, c = idx & 3;  // wc = t*64+co in [0,576)
            const uint4 d = *(const uint4*)(wt + (wc << 6) + half * 32 + c * 8);
            ushort_t* dp = &s_w[wc * 36 + c * 8];
            *(uint2*)dp       = make_uint2(d.x, d.y);
            *(uint2*)(dp + 4) = make_uint2(d.z, d.w);
        }
        __syncthreads();

#pragma unroll
        for (int t = 0; t < 9; ++t) {
            const int dy = t / 3, dx = t - dy * 3;
            FragU A[4];
#pragma unroll
            for (int mb = 0; mb < 4; ++mb) {
                const ushort_t* p = &s_w[(t * 64 + mb * 16 + n) * 36 + q * 8];
                A[mb].h[0] = *(const short4_t*)p;
                A[mb].h[1] = *(const short4_t*)(p + 4);
            }
#pragma unroll
            for (int j = 0; j < 4; ++j) {
                const int row = wv * 4 + j;
                const ushort_t* p = &s_in[((row + dy) * 18 + n + dx) * 36 + q * 8];
                FragU B;
                B.h[0] = *(const short4_t*)p;
                B.h[1] = *(const short4_t*)(p + 4);
#pragma unroll
                for (int mb = 0; mb < 4; ++mb)
                    acc[mb][j] = __builtin_amdgcn_mfma_f32_16x16x32_bf16(
                        A[mb].v, B.v, acc[mb][j], 0, 0, 0);
            }
        }
    }

    // ---- epilogue: D[m=co][n=px]: co = mb*16 + q*4 + r, px-col = n
#pragma unroll
    for (int mb = 0; mb < 4; ++mb) {
        const int co = mb * 16 + q * 4;
        const float4 bv = *(const float4*)(bias + co);
        const float bvr[4] = {bv.x, bv.y, bv.z, bv.w};
#pragma unroll
        for (int j = 0; j < 4; ++j) {
            const int gy = y0 + wv * 4 + j, gx = x0 + n;
            ushort_t* op = out + ((img + (long)gy * W + gx) << 6) + co;
            bf16 tmp[4];
#pragma unroll
            for (int r = 0; r < 4; ++r) {
                float v = acc[mb][j][r] + bvr[r];
                v = v > 0.f ? v : 0.f;
                tmp[r] = (bf16)v;
            }
            *(uint2*)op = *(uint2*)tmp;
        }
    }
}

// ---------------------------------------------------------------------------
// conv 3x3 SAME, 64->1 + bias + relu.  NHWC bf16 in, f32 out.
// ---------------------------------------------------------------------------
__global__ __launch_bounds__(256) void conv3x3_c1(
    const ushort_t* __restrict__ in,  // [B][H][W][64] bf16
    float* __restrict__ out,          // [B][H][W]
    const float* __restrict__ w,      // [64][9]  (orig [1][64][3][3])
    const float* __restrict__ bias,   // [1]
    int H, int W)
{
    __shared__ ushort_t s_in[324 * 72];  // 46,656 B
    __shared__ float s_w[576];

    const int b = blockIdx.z;
    const int x0 = blockIdx.x * 16, y0 = blockIdx.y * 16;
    const int tid = threadIdx.x;
    for (int k = tid; k < 576; k += 256) s_w[k] = w[k];

    const long img = (long)b * H * W;
    for (int idx = tid; idx < 2592; idx += 256) {
        const int p = idx >> 3, c = idx & 7;
        const int py = p / 18, px = p - py * 18;
        const int gy = y0 - 1 + py, gx = x0 - 1 + px;
        uint4 d = {0u, 0u, 0u, 0u};
        if (gy >= 0 && gy < H && gx >= 0 && gx < W)
            d = *(const uint4*)(in + ((img + (long)gy * W + gx) << 6) + c * 8);
        *(uint4*)&s_in[p * 72 + c * 8] = d;
    }
    __syncthreads();

    const int px = tid & 15, py = tid >> 4;
    float acc = 0.f;
#pragma unroll
    for (int t = 0; t < 9; ++t) {
        const int dy = t / 3, dx = t - dy * 3;
        const ushort_t* p = &s_in[((py + dy) * 18 + px + dx) * 72];
#pragma unroll
        for (int c8 = 0; c8 < 8; ++c8) {
            Frag16 f;
            f.u = *(const uint4*)(p + c8 * 8);
#pragma unroll
            for (int i = 0; i < 8; ++i) {
                float fv = __uint_as_float(((uint32)(ushort_t)f.s[i]) << 16);
                acc += fv * s_w[(c8 * 8 + i) * 9 + t];
            }
        }
    }
    float v = acc + bias[0];
    v = v > 0.f ? v : 0.f;
    out[img + (long)(y0 + py) * W + x0 + px] = v;
}

// ---------------------------------------------------------------------------
// Fused: bilinear sample of 8 instance masks, softmax over 9 logits
// (bg +BIG outside coverage), blend CPB channels of upsampled inst + bg.
// Grid: (2, 512, 4) -> blockIdx.z selects a 16-channel slice.  Softmax
// weights recomputed per slice (VALU is idle; gathers dominate).
// ---------------------------------------------------------------------------
#define CPB 16   // channels per block (64 / gridDim.z)

__global__ __launch_bounds__(256) void fuse_out(
    const float* __restrict__ inst, // [8][64][128][128]
    const float* __restrict__ bg,   // [64][512][512]
    const float* __restrict__ m,    // [8][128][128]
    const float* __restrict__ bgm,  // [512][512]
    float* __restrict__ out)        // [64][512][512]
{
    const int x = blockIdx.x * 256 + threadIdx.x;
    const int y = blockIdx.y;
    const int c0 = blockIdx.z * CPB;

    constexpr int BL[8]  = {0, 64, 128, 300, 64, 200, 32, 256};
    constexpr int BT[8]  = {0, 32, 256, 300, 128, 100, 256, 320};
    constexpr int BBW[8] = {256, 192, 320, 128, 384, 256, 160, 224};
    constexpr int BBH[8] = {256, 320, 192, 128, 256, 384, 224, 160};

    float logits[9];
    bool  ins[8];
    int   o00[8], oxs[8], oys[8];
    float wf00[8], wf01[8], wf10[8], wf11[8];
    bool any = false;

#pragma unroll
    for (int n = 0; n < 8; ++n) {
        const bool inside = (x >= BL[n]) && (x < BL[n] + BBW[n]) &&
                            (y >= BT[n]) && (y < BT[n] + BBH[n]);
        ins[n] = inside;
        float lg = 0.f;
        o00[n] = 0; oxs[n] = 0; oys[n] = 0;
        wf00[n] = wf01[n] = wf10[n] = wf11[n] = 0.f;
        if (inside) {
            any = true;
            float u = ((x - BL[n]) + 0.5f) * (128.0f / BBW[n]) - 0.5f;
            float v = ((y - BT[n]) + 0.5f) * (128.0f / BBH[n]) - 0.5f;
            u = fminf(fmaxf(u, 0.f), 127.f);
            v = fminf(fmaxf(v, 0.f), 127.f);
            int   xx0 = (int)u;  float fx = u - (float)xx0;
            int   yy0 = (int)v;  float fy = v - (float)yy0;
            o00[n] = yy0 * 128 + xx0;
            oxs[n] = (xx0 < 127) ? 1 : 0;
            oys[n] = (yy0 < 127) ? 128 : 0;
            wf00[n] = (1.f - fx) * (1.f - fy);
            wf01[n] = fx * (1.f - fy);
            wf10[n] = (1.f - fx) * fy;
            wf11[n] = fx * fy;
            const float* mp = m + n * 16384;
            lg = wf00[n] * mp[o00[n]] + wf01[n] * mp[o00[n] + oxs[n]] +
                 wf10[n] * mp[o00[n] + oys[n]] +
                 wf11[n] * mp[o00[n] + oxs[n] + oys[n]];
        }
        logits[n] = lg;
    }
    logits[8] = bgm[y * 512 + x] + (any ? 0.f : BIG);

    float mx = logits[0];
#pragma unroll
    for (int i = 1; i < 9; ++i) mx = fmaxf(mx, logits[i]);
    float wgt[9], s = 0.f;
#pragma unroll
    for (int i = 0; i < 9; ++i) { wgt[i] = __expf(logits[i] - mx); s += wgt[i]; }
    const float inv = 1.f / s;
#pragma unroll
    for (int i = 0; i < 9; ++i) wgt[i] *= inv;

#pragma unroll
    for (int n = 0; n < 8; ++n) {
        wf00[n] *= wgt[n]; wf01[n] *= wgt[n];
        wf10[n] *= wgt[n]; wf11[n] *= wgt[n];
    }

    const long pix = (long)y * 512 + x;
#pragma unroll 4
    for (int cc = 0; cc < CPB; ++cc) {
        const int c = c0 + cc;
        float o = wgt[8] * bg[(long)c * 262144 + pix];
#pragma unroll
        for (int n = 0; n < 8; ++n) {
            if (ins[n]) {
                const float* p = inst + (long)(n * 64 + c) * 16384 + o00[n];
                o += wf00[n] * p[0] + wf01[n] * p[oxs[n]] +
                     wf10[n] * p[oys[n]] + wf11[n] * p[oxs[n] + oys[n]];
            }
        }
        __builtin_nontemporal_store(o, &out[(long)c * 262144 + pix]);
    }
}

// ---------------------------------------------------------------------------
extern "C" void kernel_launch(void* const* d_in, const int* in_sizes, int n_in,
                              void* d_out, int out_size, void* d_ws, size_t ws_size,
                              hipStream_t stream)
{
    (void)in_sizes; (void)n_in; (void)out_size; (void)ws_size;

    const float* instf = (const float*)d_in[0];   // 8x64x128x128
    const float* bgf   = (const float*)d_in[1];   // 1x64x512x512
    const float* iw1   = (const float*)d_in[2];
    const float* ib1   = (const float*)d_in[3];
    const float* iw2   = (const float*)d_in[4];
    const float* ib2   = (const float*)d_in[5];
    const float* iw3   = (const float*)d_in[6];
    const float* ib3   = (const float*)d_in[7];
    const float* bw1   = (const float*)d_in[8];
    const float* bb1   = (const float*)d_in[9];
    const float* bw2   = (const float*)d_in[10];
    const float* bb2   = (const float*)d_in[11];
    const float* bw3   = (const float*)d_in[12];
    const float* bb3   = (const float*)d_in[13];

    // workspace layout (68,681,728 B):
    //   R1 [0, 33.55M):  instN(16.78M)+y2(16.78M) -> bgN -> bg2
    //   R2 [33.55M, 67.1M): y1(16.78M) -> bg1(33.55M)
    //   minst f32 @67,108,864 (0.5M)
    //   bgmask f32 @67,633,152 (1M)   [wt bf16 aliased here: dead before
    //                                  bgmask is written at bg layer-3]
    char* ws = (char*)d_ws;
    ushort_t* instN = (ushort_t*)(ws);                  // 8x128x128x64 bf16
    ushort_t* y2    = (ushort_t*)(ws + 16777216);
    ushort_t* y1    = (ushort_t*)(ws + 33554432);
    ushort_t* bgN   = (ushort_t*)(ws);                  // 512x512x64 bf16
    ushort_t* bg1   = (ushort_t*)(ws + 33554432);
    ushort_t* bg2   = (ushort_t*)(ws);
    float*    minst  = (float*)(ws + 67108864);
    float*    bgmask = (float*)(ws + 67633152);
    ushort_t* wt0 = (ushort_t*)(ws + 67633152);         // aliased w/ bgmask
    ushort_t* wt1 = wt0 + 36864;
    ushort_t* wt2 = wt0 + 2 * 36864;
    ushort_t* wt3 = wt0 + 3 * 36864;

    // weight transforms
    wtrans<<<144, 256, 0, stream>>>(iw1, wt0);
    wtrans<<<144, 256, 0, stream>>>(iw2, wt1);
    wtrans<<<144, 256, 0, stream>>>(bw1, wt2);
    wtrans<<<144, 256, 0, stream>>>(bw2, wt3);

    // instance pipeline (8x 128x128)
    nchw_to_nhwc<<<dim3(2, 128, 8), 256, 0, stream>>>(instf, instN, 128, 128);
    conv3x3_mfma<<<dim3(8, 8, 8), 256, 0, stream>>>(instN, y1, wt0, ib1, 128, 128);
    conv3x3_mfma<<<dim3(8, 8, 8), 256, 0, stream>>>(y1, y2, wt1, ib2, 128, 128);
    conv3x3_c1  <<<dim3(8, 8, 8), 256, 0, stream>>>(y2, minst, iw3, ib3, 128, 128);

    // bg pipeline (512x512)
    nchw_to_nhwc<<<dim3(8, 512, 1), 256, 0, stream>>>(bgf, bgN, 512, 512);
    conv3x3_mfma<<<dim3(32, 32, 1), 256, 0, stream>>>(bgN, bg1, wt2, bb1, 512, 512);
    conv3x3_mfma<<<dim3(32, 32, 1), 256, 0, stream>>>(bg1, bg2, wt3, bb2, 512, 512);
    conv3x3_c1  <<<dim3(32, 32, 1), 256, 0, stream>>>(bg2, bgmask, bw3, bb3, 512, 512);

    // fused resize + softmax + blend  (z = 4 channel slices of 16)
    fuse_out<<<dim3(2, 512, 4), 256, 0, stream>>>(instf, bgf, minst, bgmask, (float*)d_out);
}

// Round 7
// 449.152 us; speedup vs baseline: 1.1748x; 1.1748x over previous
//
#include <hip/hip_runtime.h>
#include <hip/hip_bf16.h>

typedef __hip_bfloat16 bf16;
typedef unsigned short ushort_t;
typedef unsigned int uint32;

typedef short short4_t __attribute__((ext_vector_type(4)));
typedef short short8_t __attribute__((ext_vector_type(8)));
typedef float float4_t __attribute__((ext_vector_type(4)));

union FragU { short4_t h[2]; short8_t v; };
union Frag16 { short8_t v; short s[8]; uint4 u; };

#define BIG 100000.0f

// ---------------------------------------------------------------------------
// weights [64co][64ci][3][3] f32  ->  [9tap][64co][64ci] bf16 bits
// ---------------------------------------------------------------------------
__global__ __launch_bounds__(256) void wtrans(const float* __restrict__ w,
                                              ushort_t* __restrict__ dst)
{
    int idx = blockIdx.x * 256 + threadIdx.x;  // 36864 total
    if (idx < 36864) {
        int ci = idx & 63, co = (idx >> 6) & 63, t = idx >> 12;
        bf16 h = (bf16)w[(co * 64 + ci) * 9 + t];
        dst[idx] = *(ushort_t*)&h;
    }
}

// ---------------------------------------------------------------------------
// NCHW f32 -> NHWC bf16 (C=64).  Block: one row-y, 64 x.  LDS transpose.
// ---------------------------------------------------------------------------
__global__ __launch_bounds__(256) void nchw_to_nhwc(
    const float* __restrict__ in,   // [B][64][H][W]
    ushort_t* __restrict__ out,     // [B][H][W][64]
    int H, int W)
{
    __shared__ ushort_t s[64 * 66];
    const int b = blockIdx.z, y = blockIdx.y, x0 = blockIdx.x * 64;
    const int tid = threadIdx.x;
    const long ibase = (long)b * 64 * H * W + (long)y * W + x0;
    {
        const int x = tid & 63, dc = tid >> 6;
        for (int c = dc; c < 64; c += 4) {
            bf16 h = (bf16)in[ibase + (long)c * H * W + x];
            s[c * 66 + x] = *(ushort_t*)&h;
        }
    }
    __syncthreads();
    {
        const int c = tid & 63, dx = tid >> 6;
        const long obase = ((long)b * H * W + (long)y * W + x0) * 64;
        for (int x = dx; x < 64; x += 4)
            out[obase + (long)x * 64 + c] = s[c * 66 + x];
    }
}

// ---------------------------------------------------------------------------
// conv 3x3 SAME, 64->64 + bias + relu, NHWC bf16, MFMA 16x16x32.
// ---------------------------------------------------------------------------
__global__ __launch_bounds__(256) void conv3x3_mfma(
    const ushort_t* __restrict__ in,   // [B][H][W][64] bf16
    ushort_t* __restrict__ out,        // [B][H][W][64] bf16
    const ushort_t* __restrict__ wt,   // [9][64][64] bf16
    const float* __restrict__ bias,    // [64] f32
    int H, int W)
{
    __shared__ ushort_t s_in[324 * 36];     // 23,328 B
    __shared__ ushort_t s_w[9 * 64 * 36];   // 41,472 B  (total 64,800 <= 64K)

    const int b = blockIdx.z;
    const int x0 = blockIdx.x * 16, y0 = blockIdx.y * 16;
    const int tid = threadIdx.x;
    const int lane = tid & 63, wv = tid >> 6;
    const int n = lane & 15, q = lane >> 4;   // n: M or N index, q: k-quad

    const long img = (long)b * H * W;

    float4_t acc[4][4];
#pragma unroll
    for (int mb = 0; mb < 4; ++mb)
#pragma unroll
        for (int j = 0; j < 4; ++j) acc[mb][j] = (float4_t){0.f, 0.f, 0.f, 0.f};

    for (int half = 0; half < 2; ++half) {
        __syncthreads();
        // ---- stage input patch: 324 px x 32 ci = 324*4 = 1296 chunks of 8
        for (int idx = tid; idx < 1296; idx += 256) {
            const int p = idx >> 2, c = idx & 3;
            const int py = p / 18, px = p - py * 18;
            const int gy = y0 - 1 + py, gx = x0 - 1 + px;
            uint4 d = {0u, 0u, 0u, 0u};
            if (gy >= 0 && gy < H && gx >= 0 && gx < W)
                d = *(const uint4*)(in + ((img + (long)gy * W + gx) << 6) + half * 32 + c * 8);
            ushort_t* dp = &s_in[p * 36 + c * 8];
            *(uint2*)dp       = make_uint2(d.x, d.y);
            *(uint2*)(dp + 4) = make_uint2(d.z, d.w);
        }
        // ---- stage weights: 9*64 = 576 rows x 32 ci = 2304 chunks
        for (int idx = tid; idx < 2304; idx += 256) {
            const int wc = idx >> 2, c = idx & 3;  // wc = t*64+co in [0,576)
            const uint4 d = *(const uint4*)(wt + (wc << 6) + half * 32 + c * 8);
            ushort_t* dp = &s_w[wc * 36 + c * 8];
            *(uint2*)dp       = make_uint2(d.x, d.y);
            *(uint2*)(dp + 4) = make_uint2(d.z, d.w);
        }
        __syncthreads();

#pragma unroll
        for (int t = 0; t < 9; ++t) {
            const int dy = t / 3, dx = t - dy * 3;
            FragU A[4];
#pragma unroll
            for (int mb = 0; mb < 4; ++mb) {
                const ushort_t* p = &s_w[(t * 64 + mb * 16 + n) * 36 + q * 8];
                A[mb].h[0] = *(const short4_t*)p;
                A[mb].h[1] = *(const short4_t*)(p + 4);
            }
#pragma unroll
            for (int j = 0; j < 4; ++j) {
                const int row = wv * 4 + j;
                const ushort_t* p = &s_in[((row + dy) * 18 + n + dx) * 36 + q * 8];
                FragU B;
                B.h[0] = *(const short4_t*)p;
                B.h[1] = *(const short4_t*)(p + 4);
#pragma unroll
                for (int mb = 0; mb < 4; ++mb)
                    acc[mb][j] = __builtin_amdgcn_mfma_f32_16x16x32_bf16(
                        A[mb].v, B.v, acc[mb][j], 0, 0, 0);
            }
        }
    }

    // ---- epilogue: D[m=co][n=px]: co = mb*16 + q*4 + r, px-col = n
#pragma unroll
    for (int mb = 0; mb < 4; ++mb) {
        const int co = mb * 16 + q * 4;
        const float4 bv = *(const float4*)(bias + co);
        const float bvr[4] = {bv.x, bv.y, bv.z, bv.w};
#pragma unroll
        for (int j = 0; j < 4; ++j) {
            const int gy = y0 + wv * 4 + j, gx = x0 + n;
            ushort_t* op = out + ((img + (long)gy * W + gx) << 6) + co;
            bf16 tmp[4];
#pragma unroll
            for (int r = 0; r < 4; ++r) {
                float v = acc[mb][j][r] + bvr[r];
                v = v > 0.f ? v : 0.f;
                tmp[r] = (bf16)v;
            }
            *(uint2*)op = *(uint2*)tmp;
        }
    }
}

// ---------------------------------------------------------------------------
// conv 3x3 SAME, 64->1 + bias + relu.  NHWC bf16 in, f32 out.
// ---------------------------------------------------------------------------
__global__ __launch_bounds__(256) void conv3x3_c1(
    const ushort_t* __restrict__ in,  // [B][H][W][64] bf16
    float* __restrict__ out,          // [B][H][W]
    const float* __restrict__ w,      // [64][9]  (orig [1][64][3][3])
    const float* __restrict__ bias,   // [1]
    int H, int W)
{
    __shared__ ushort_t s_in[324 * 72];  // 46,656 B
    __shared__ float s_w[576];

    const int b = blockIdx.z;
    const int x0 = blockIdx.x * 16, y0 = blockIdx.y * 16;
    const int tid = threadIdx.x;
    for (int k = tid; k < 576; k += 256) s_w[k] = w[k];

    const long img = (long)b * H * W;
    for (int idx = tid; idx < 2592; idx += 256) {
        const int p = idx >> 3, c = idx & 7;
        const int py = p / 18, px = p - py * 18;
        const int gy = y0 - 1 + py, gx = x0 - 1 + px;
        uint4 d = {0u, 0u, 0u, 0u};
        if (gy >= 0 && gy < H && gx >= 0 && gx < W)
            d = *(const uint4*)(in + ((img + (long)gy * W + gx) << 6) + c * 8);
        *(uint4*)&s_in[p * 72 + c * 8] = d;
    }
    __syncthreads();

    const int px = tid & 15, py = tid >> 4;
    float acc = 0.f;
#pragma unroll
    for (int t = 0; t < 9; ++t) {
        const int dy = t / 3, dx = t - dy * 3;
        const ushort_t* p = &s_in[((py + dy) * 18 + px + dx) * 72];
#pragma unroll
        for (int c8 = 0; c8 < 8; ++c8) {
            Frag16 f;
            f.u = *(const uint4*)(p + c8 * 8);
#pragma unroll
            for (int i = 0; i < 8; ++i) {
                float fv = __uint_as_float(((uint32)(ushort_t)f.s[i]) << 16);
                acc += fv * s_w[(c8 * 8 + i) * 9 + t];
            }
        }
    }
    float v = acc + bias[0];
    v = v > 0.f ? v : 0.f;
    out[img + (long)(y0 + py) * W + x0 + px] = v;
}

// ---------------------------------------------------------------------------
// Fused: bilinear sample of 8 instance masks, softmax over 9 logits
// (bg +BIG outside coverage), blend CPB channels of upsampled inst + bg.
// BRANCHLESS gather: weights are 0 outside a box and offsets are 0
// (lane-uniform -> broadcast, cache-hit), so we always issue all 32 taps
// per channel into independent registers (one waitcnt, full pipelining),
// then combine.  Work per pixel is uniform -> no straggler blocks.
// ---------------------------------------------------------------------------
#define CPB 16   // channels per block (64 / gridDim.z)

__global__ __launch_bounds__(256) void fuse_out(
    const float* __restrict__ inst, // [8][64][128][128]
    const float* __restrict__ bg,   // [64][512][512]
    const float* __restrict__ m,    // [8][128][128]
    const float* __restrict__ bgm,  // [512][512]
    float* __restrict__ out)        // [64][512][512]
{
    const int x = blockIdx.x * 256 + threadIdx.x;
    const int y = blockIdx.y;
    const int c0 = blockIdx.z * CPB;

    constexpr int BL[8]  = {0, 64, 128, 300, 64, 200, 32, 256};
    constexpr int BT[8]  = {0, 32, 256, 300, 128, 100, 256, 320};
    constexpr int BBW[8] = {256, 192, 320, 128, 384, 256, 160, 224};
    constexpr int BBH[8] = {256, 320, 192, 128, 256, 384, 224, 160};

    float logits[9];
    int   o00[8], oxs[8], oys[8];
    float wf00[8], wf01[8], wf10[8], wf11[8];
    bool any = false;

#pragma unroll
    for (int n = 0; n < 8; ++n) {
        const bool inside = (x >= BL[n]) && (x < BL[n] + BBW[n]) &&
                            (y >= BT[n]) && (y < BT[n] + BBH[n]);
        float lg = 0.f;
        o00[n] = 0; oxs[n] = 0; oys[n] = 0;
        wf00[n] = wf01[n] = wf10[n] = wf11[n] = 0.f;
        if (inside) {
            any = true;
            float u = ((x - BL[n]) + 0.5f) * (128.0f / BBW[n]) - 0.5f;
            float v = ((y - BT[n]) + 0.5f) * (128.0f / BBH[n]) - 0.5f;
            u = fminf(fmaxf(u, 0.f), 127.f);
            v = fminf(fmaxf(v, 0.f), 127.f);
            int   xx0 = (int)u;  float fx = u - (float)xx0;
            int   yy0 = (int)v;  float fy = v - (float)yy0;
            o00[n] = yy0 * 128 + xx0;
            oxs[n] = (xx0 < 127) ? 1 : 0;
            oys[n] = (yy0 < 127) ? 128 : 0;
            wf00[n] = (1.f - fx) * (1.f - fy);
            wf01[n] = fx * (1.f - fy);
            wf10[n] = (1.f - fx) * fy;
            wf11[n] = fx * fy;
            const float* mp = m + n * 16384;
            lg = wf00[n] * mp[o00[n]] + wf01[n] * mp[o00[n] + oxs[n]] +
                 wf10[n] * mp[o00[n] + oys[n]] +
                 wf11[n] * mp[o00[n] + oxs[n] + oys[n]];
        }
        logits[n] = lg;
    }
    logits[8] = bgm[y * 512 + x] + (any ? 0.f : BIG);

    float mx = logits[0];
#pragma unroll
    for (int i = 1; i < 9; ++i) mx = fmaxf(mx, logits[i]);
    float wgt[9], s = 0.f;
#pragma unroll
    for (int i = 0; i < 9; ++i) { wgt[i] = __expf(logits[i] - mx); s += wgt[i]; }
    const float inv = 1.f / s;
#pragma unroll
    for (int i = 0; i < 9; ++i) wgt[i] *= inv;

#pragma unroll
    for (int n = 0; n < 8; ++n) {
        wf00[n] *= wgt[n]; wf01[n] *= wgt[n];
        wf10[n] *= wgt[n]; wf11[n] *= wgt[n];
    }

    const long pix = (long)y * 512 + x;

    // per-box gather pointers for channel c0 (advance by 16384 per channel)
    const float* bp[8];
#pragma unroll
    for (int n = 0; n < 8; ++n)
        bp[n] = inst + (long)(n * 64 + c0) * 16384 + o00[n];
    const float* bgp  = bg  + (long)c0 * 262144 + pix;
    float*       outp = out + (long)c0 * 262144 + pix;

    for (int cc = 0; cc < CPB; ++cc) {
        // ---- load phase: all taps into independent regs (batched VMEM)
        float t0[8], t1[8], t2[8], t3[8];
#pragma unroll
        for (int n = 0; n < 8; ++n) {
            const float* p = bp[n];
            t0[n] = p[0];
            t1[n] = p[oxs[n]];
            t2[n] = p[oys[n]];
            t3[n] = p[oxs[n] + oys[n]];
            bp[n] += 16384;
        }
        float o = wgt[8] * bgp[0];
        // ---- combine phase
#pragma unroll
        for (int n = 0; n < 8; ++n)
            o += wf00[n] * t0[n] + wf01[n] * t1[n] +
                 wf10[n] * t2[n] + wf11[n] * t3[n];
        __builtin_nontemporal_store(o, outp);
        bgp  += 262144;
        outp += 262144;
    }
}

// ---------------------------------------------------------------------------
extern "C" void kernel_launch(void* const* d_in, const int* in_sizes, int n_in,
                              void* d_out, int out_size, void* d_ws, size_t ws_size,
                              hipStream_t stream)
{
    (void)in_sizes; (void)n_in; (void)out_size; (void)ws_size;

    const float* instf = (const float*)d_in[0];   // 8x64x128x128
    const float* bgf   = (const float*)d_in[1];   // 1x64x512x512
    const float* iw1   = (const float*)d_in[2];
    const float* ib1   = (const float*)d_in[3];
    const float* iw2   = (const float*)d_in[4];
    const float* ib2   = (const float*)d_in[5];
    const float* iw3   = (const float*)d_in[6];
    const float* ib3   = (const float*)d_in[7];
    const float* bw1   = (const float*)d_in[8];
    const float* bb1   = (const float*)d_in[9];
    const float* bw2   = (const float*)d_in[10];
    const float* bb2   = (const float*)d_in[11];
    const float* bw3   = (const float*)d_in[12];
    const float* bb3   = (const float*)d_in[13];

    // workspace layout (68,681,728 B):
    //   R1 [0, 33.55M):  instN(16.78M)+y2(16.78M) -> bgN -> bg2
    //   R2 [33.55M, 67.1M): y1(16.78M) -> bg1(33.55M)
    //   minst f32 @67,108,864 (0.5M)
    //   bgmask f32 @67,633,152 (1M)   [wt bf16 aliased here: dead before
    //                                  bgmask is written at bg layer-3]
    char* ws = (char*)d_ws;
    ushort_t* instN = (ushort_t*)(ws);                  // 8x128x128x64 bf16
    ushort_t* y2    = (ushort_t*)(ws + 16777216);
    ushort_t* y1    = (ushort_t*)(ws + 33554432);
    ushort_t* bgN   = (ushort_t*)(ws);                  // 512x512x64 bf16
    ushort_t* bg1   = (ushort_t*)(ws + 33554432);
    ushort_t* bg2   = (ushort_t*)(ws);
    float*    minst  = (float*)(ws + 67108864);
    float*    bgmask = (float*)(ws + 67633152);
    ushort_t* wt0 = (ushort_t*)(ws + 67633152);         // aliased w/ bgmask
    ushort_t* wt1 = wt0 + 36864;
    ushort_t* wt2 = wt0 + 2 * 36864;
    ushort_t* wt3 = wt0 + 3 * 36864;

    // weight transforms
    wtrans<<<144, 256, 0, stream>>>(iw1, wt0);
    wtrans<<<144, 256, 0, stream>>>(iw2, wt1);
    wtrans<<<144, 256, 0, stream>>>(bw1, wt2);
    wtrans<<<144, 256, 0, stream>>>(bw2, wt3);

    // instance pipeline (8x 128x128)
    nchw_to_nhwc<<<dim3(2, 128, 8), 256, 0, stream>>>(instf, instN, 128, 128);
    conv3x3_mfma<<<dim3(8, 8, 8), 256, 0, stream>>>(instN, y1, wt0, ib1, 128, 128);
    conv3x3_mfma<<<dim3(8, 8, 8), 256, 0, stream>>>(y1, y2, wt1, ib2, 128, 128);
    conv3x3_c1  <<<dim3(8, 8, 8), 256, 0, stream>>>(y2, minst, iw3, ib3, 128, 128);

    // bg pipeline (512x512)
    nchw_to_nhwc<<<dim3(8, 512, 1), 256, 0, stream>>>(bgf, bgN, 512, 512);
    conv3x3_mfma<<<dim3(32, 32, 1), 256, 0, stream>>>(bgN, bg1, wt2, bb1, 512, 512);
    conv3x3_mfma<<<dim3(32, 32, 1), 256, 0, stream>>>(bg1, bg2, wt3, bb2, 512, 512);
    conv3x3_c1  <<<dim3(32, 32, 1), 256, 0, stream>>>(bg2, bgmask, bw3, bb3, 512, 512);

    // fused resize + softmax + blend  (z = 4 channel slices of 16)
    fuse_out<<<dim3(2, 512, 4), 256, 0, stream>>>(instf, bgf, minst, bgmask, (float*)d_out);
}